// Round 4
// baseline (260.969 us; speedup 1.0000x reference)
//
#include <hip/hip_runtime.h>
#include <hip/hip_bf16.h>
#include <hip/hip_cooperative_groups.h>

namespace cg = cooperative_groups;

#define D 512
#define NWAY 64
#define KSHOT 16
#define NQ 8192

typedef __bf16 bf16_t;
typedef __bf16 bf16x8_t __attribute__((ext_vector_type(8)));
typedef __bf16 bf16x4_t __attribute__((ext_vector_type(4)));
typedef float  f32x4    __attribute__((ext_vector_type(4)));

typedef __attribute__((address_space(1))) const void gv_t;
typedef __attribute__((address_space(3))) void lv_t;
__device__ __forceinline__ void ld16(const void* g, void* l) {
    __builtin_amdgcn_global_load_lds((gv_t*)g, (lv_t*)l, 16, 0, 0);
}

// Bsw: [ck(8)][n(576)][seg(8)] bf16, off = ck*36864 + n*64 + ((s^(n&7))*8)
//   rows 0..511 = W (bf16), rows 512..575 = G_c = W^T p_c

// ---------------------------------------------------------------- K_FUSED
// Single cooperative launch, 256 blocks x 512 thr, 1 block/CU (LDS-limited).
// Phase 1: P (quarter-dots) + W->bf16 swizzle (2 rows/block).
// Phase 2: G_c cols + ph_c.   Phase 3: R1 k_main body (proven).
// Grid syncs replace 2 kernel-launch boundaries (~2.8 us each); query
// A-preload issues at kernel start so its HBM latency hides under preps.
__global__ __launch_bounds__(512, 2) void k_fused(
    const float* __restrict__ sup, const float* __restrict__ query,
    const float* __restrict__ W, const float* __restrict__ bias,
    bf16_t* __restrict__ Bsw, float* __restrict__ ph,
    float* __restrict__ Pg, float* __restrict__ out)
{
    __shared__ __align__(16) bf16_t Bb[2][36864]; // 147,456 B
    __shared__ __align__(16) bf16_t Ab[2][2048];  //   8,192 B
    __shared__ float qln[4][32];    //     512 B
    __shared__ float phs[NWAY];     //     256 B
    __shared__ float bs[576];       //   2,304 B   (total 158,720 B)

    const int t = threadIdx.x, bm = blockIdx.x;
    cg::grid_group grid = cg::this_grid();

    // ---- A preload: issue early; f32 held in regs through phase 1
    const int am = t >> 4;                 // 0..31
    const int ac4 = t & 15;
    const int a_lds = am * 64 + (((ac4 >> 1) ^ (am & 7)) * 8) + (ac4 & 1) * 4;
    const float* aqp = query + (size_t)(bm * 32 + am) * D + ac4 * 4;
    f32x4 av[8];
#pragma unroll
    for (int ck = 0; ck < 8; ++ck) av[ck] = *(const f32x4*)(aqp + ck * 64);

    // ================= PHASE 1: P + W-convert =================
    {
        const int c = bm >> 2, jq4 = bm & 3;
        float* cm = (float*)&Bb[0][0];                 // 2 KB alias
        {   // cm_c[t] = mean over shots
            float s = 0.f;
            const float* sp = sup + (size_t)c * KSHOT * D + t;
#pragma unroll
            for (int j = 0; j < KSHOT; ++j) s += sp[(size_t)j * D];
            cm[t] = s * (1.0f / KSHOT);
        }
        __syncthreads();
        {   // P: 128 j per block, 4 lanes/j (128-dim quarter-dots)
            const int j = jq4 * 128 + (t >> 2), qtr = t & 3;
            const f32x4* wr = (const f32x4*)(W + (size_t)j * D + qtr * 128);
            const f32x4* cr = (const f32x4*)(cm + qtr * 128);
            float ps = 0.f;
#pragma unroll 8
            for (int i = 0; i < 32; ++i) {
                f32x4 a = cr[i], wv = wr[i];
                ps += a[0]*wv[0] + a[1]*wv[1] + a[2]*wv[2] + a[3]*wv[3];
            }
            ps += __shfl_xor(ps, 1); ps += __shfl_xor(ps, 2);
            if (qtr == 0) Pg[(size_t)c * D + j] = ps + bias[j];
        }
        if (t < 128) {                     // W -> bf16 swizzle, 2 rows/block
            const int n = bm * 2 + (t >> 6);
            const int sl = t & 63;
            const f32x4* wp = (const f32x4*)(W + (size_t)n * D + sl * 8);
            f32x4 v0 = wp[0], v1 = wp[1];
            bf16x8_t hv = { (bf16_t)v0[0], (bf16_t)v0[1], (bf16_t)v0[2], (bf16_t)v0[3],
                            (bf16_t)v1[0], (bf16_t)v1[1], (bf16_t)v1[2], (bf16_t)v1[3] };
            const int ckk = sl >> 3, ss = sl & 7;
            *(bf16x8_t*)(Bsw + (size_t)ckk * 36864 + n * 64 + ((ss ^ (n & 7)) * 8)) = hv;
        }
    }

    // convert A to bf16 while phase-1 stores drain
    bf16x4_t areg[8];
#pragma unroll
    for (int ck = 0; ck < 8; ++ck)
        areg[ck] = (bf16x4_t){ (bf16_t)av[ck][0], (bf16_t)av[ck][1],
                               (bf16_t)av[ck][2], (bf16_t)av[ck][3] };

    __threadfence();
    grid.sync();

    // ================= PHASE 2: G + ph =================
    {
        const int c = bm >> 2, kc = bm & 3;
        float* Pl  = (float*)&Bb[0][0];        // 2 KB
        float* sGm = (float*)&Bb[0][4096];     // 2 KB (byte off 8192)
        float* red = (float*)&Bb[0][8192];     // 16 B (byte off 16384)
        Pl[t] = Pg[(size_t)c * D + t];
        __syncthreads();

        const int kl = t & 127, jq = t >> 7;
        const int k = kc * 128 + kl;
        float g = 0.f;
        const float* wcol = W + (size_t)jq * 128 * D + k;
#pragma unroll 8
        for (int j = 0; j < 128; ++j)
            g += Pl[jq * 128 + j] * wcol[(size_t)j * D];
        sGm[jq * 128 + kl] = g;

        if (kc == 0 && t < 256) {              // ph partial
            float v1 = Pl[t], v2 = Pl[t + 256];
            float pp = v1*v1 - 2.0f*bias[t]*v1 + v2*v2 - 2.0f*bias[t+256]*v2;
#pragma unroll
            for (int off = 32; off; off >>= 1) pp += __shfl_xor(pp, off);
            if ((t & 63) == 0) red[t >> 6] = pp;
        }
        __syncthreads();

        if (t < 128) {
            const float gt = sGm[t] + sGm[128 + t] + sGm[256 + t] + sGm[384 + t];
            const int k2 = kc * 128 + t;
            const int n = 512 + c;
            const int ckk = k2 >> 6, ss = (k2 >> 3) & 7, e = k2 & 7;
            Bsw[(size_t)ckk * 36864 + n * 64 + ((ss ^ (c & 7)) * 8) + e] = (bf16_t)gt;
        }
        if (kc == 0 && t == 0) ph[c] = red[0] + red[1] + red[2] + red[3];
    }

    __threadfence();
    grid.sync();

    // ================= PHASE 3: main GEMM (R1 body) =================
    bs[t] = bias[t];
    if (t < NWAY) { bs[512 + t] = 0.f; phs[t] = ph[t]; }

    const int l = t & 63, w = t >> 6;
    const int wm = w & 1, wn = w >> 1;
    const int r15 = l & 15, quad = l >> 4;

    const int xt0 = ((quad ^ (r15 & 7)) * 8);
    const int xt1 = (((4 + quad) ^ (r15 & 7)) * 8);
    const int aoff = (wm * 16 + r15) * 64;
    const int boff = (wn * 144 + r15) * 64;
    const int wb = w * 4608 + l * 8;

    f32x4 acc[9];
#pragma unroll
    for (int i = 0; i < 9; ++i) acc[i] = (f32x4){0.f, 0.f, 0.f, 0.f};

    // prologue: stage chunk 0 into buffer 0 (grid.sync above ordered
    // phase-2 LDS reads before these overwrites)
    {
#pragma unroll
        for (int i = 0; i < 9; ++i)
            ld16(Bsw + wb + i * 512, &Bb[0][wb + i * 512]);
        *(bf16x4_t*)(&Ab[0][a_lds]) = areg[0];
    }
    __syncthreads();   // drains vmcnt(0)+lgkmcnt(0): chunk 0 ready

#pragma unroll
    for (int ck = 0; ck < 8; ++ck) {
        const int cur = ck & 1;
        if (ck < 7) {
            const int nxt = cur ^ 1;
            const size_t sb = (size_t)(ck + 1) * 36864;
#pragma unroll
            for (int i = 0; i < 9; ++i)
                ld16(Bsw + sb + wb + i * 512, &Bb[nxt][wb + i * 512]);
            *(bf16x4_t*)(&Ab[nxt][a_lds]) = areg[ck + 1];
        }

        bf16x8_t a0 = *(const bf16x8_t*)(&Ab[cur][aoff + xt0]);
        bf16x8_t a1 = *(const bf16x8_t*)(&Ab[cur][aoff + xt1]);
#pragma unroll
        for (int tt = 0; tt < 9; ++tt) {
            bf16x8_t b0 = *(const bf16x8_t*)(&Bb[cur][boff + tt * 1024 + xt0]);
            bf16x8_t b1 = *(const bf16x8_t*)(&Bb[cur][boff + tt * 1024 + xt1]);
            acc[tt] = __builtin_amdgcn_mfma_f32_16x16x32_bf16(a0, b0, acc[tt], 0, 0, 0);
            acc[tt] = __builtin_amdgcn_mfma_f32_16x16x32_bf16(a1, b1, acc[tt], 0, 0, 0);
        }

        if (ck < 7) __syncthreads();
    }

    // ---- qn = sum over W-cols of (e + bias)^2 ; constant bound, masked ----
    float qp[4] = {0.f, 0.f, 0.f, 0.f};
#pragma unroll
    for (int tt = 0; tt < 9; ++tt) {
        const int colbase = wn * 144 + tt * 16;
        const float m = (colbase < 512) ? 1.f : 0.f;   // wave-uniform
        const float bv = bs[colbase + r15];
#pragma unroll
        for (int reg = 0; reg < 4; ++reg) {
            float v = acc[tt][reg] + bv;
            qp[reg] += m * v * v;
        }
    }
#pragma unroll
    for (int reg = 0; reg < 4; ++reg) {
        float s = qp[reg];
        s += __shfl_xor(s, 1); s += __shfl_xor(s, 2);
        s += __shfl_xor(s, 4); s += __shfl_xor(s, 8);
        if (r15 == 0) qln[wn][wm * 16 + quad * 4 + reg] = s;
    }
    __syncthreads();

    // ---- wn==3 waves write dists: qt + ph[c] - 2 * (q.G_c) ----
    if (wn == 3) {
#pragma unroll
        for (int reg = 0; reg < 4; ++reg) {
            const int row_local = quad * 4 + reg;
            const float qt = qln[0][wm * 16 + row_local] + qln[1][wm * 16 + row_local] +
                             qln[2][wm * 16 + row_local] + qln[3][wm * 16 + row_local];
            const int rowg = bm * 32 + wm * 16 + row_local;
#pragma unroll
            for (int tg = 0; tg < 4; ++tg) {
                const int c = tg * 16 + r15;
                out[(size_t)rowg * NWAY + c] = qt + phs[c] - 2.0f * acc[5 + tg][reg];
            }
        }
    }
}

// ---------------------------------------------------------------- launch
extern "C" void kernel_launch(void* const* d_in, const int* in_sizes, int n_in,
                              void* d_out, int out_size, void* d_ws, size_t ws_size,
                              hipStream_t stream)
{
    const float* support = (const float*)d_in[0];
    const float* query   = (const float*)d_in[1];
    const float* W       = (const float*)d_in[2];
    const float* bias    = (const float*)d_in[3];
    float* out = (float*)d_out;

    char* ws = (char*)d_ws;
    bf16_t* Bsw = (bf16_t*)ws;                    // 589,824 B
    float*  ph  = (float*)(ws + 589824);          //     256 B
    float*  Pg  = (float*)(ws + 589824 + 256);    // 131,072 B

    void* kargs[] = { (void*)&support, (void*)&query, (void*)&W, (void*)&bias,
                      (void*)&Bsw, (void*)&ph, (void*)&Pg, (void*)&out };
    hipLaunchCooperativeKernel((const void*)k_fused, dim3(256), dim3(512),
                               kargs, 0, stream);
}

// Round 5
// 99.315 us; speedup vs baseline: 2.6277x; 2.6277x over previous
//
#include <hip/hip_runtime.h>
#include <hip/hip_bf16.h>

#define D 512
#define NWAY 64
#define KSHOT 16
#define NQ 8192

typedef __bf16 bf16_t;
typedef __bf16 bf16x8_t __attribute__((ext_vector_type(8)));
typedef __bf16 bf16x4_t __attribute__((ext_vector_type(4)));
typedef float  f32x4    __attribute__((ext_vector_type(4)));

typedef __attribute__((address_space(1))) const void gv_t;
typedef __attribute__((address_space(3))) void lv_t;
__device__ __forceinline__ void ld16(const void* g, void* l) {
    __builtin_amdgcn_global_load_lds((gv_t*)g, (lv_t*)l, 16, 0, 0);
}

// Bsw: [ck(8)][n(512)][seg(8)] bf16, off = ck*32768 + n*64 + ((s^(n&7))*8)
//   (W rows only — the G columns are gone; cross term computed in-block)
// Psw: [c(64)][pos(64)][e(8)] bf16, off = c*512 + pos*8 + (k&7),
//   pos = (s&~7)|((s&7)^(c&7)), s = k>>3  (row-swizzled, staged verbatim)

// ---------------------------------------------------------------- K_PREP
// blocks 0..255: P blocks (c=b>>2, jq=b&3): P_c[j] = cm_c.W_j + b_j -> Psw bf16
// blocks 256..383: W -> bf16 swizzled into Bsw (4 rows/block)
__global__ __launch_bounds__(256) void k_prep(
    const float* __restrict__ sup, const float* __restrict__ W,
    const float* __restrict__ bias, bf16_t* __restrict__ Bsw,
    bf16_t* __restrict__ Psw)
{
    const int b = blockIdx.x, t = threadIdx.x;

    if (b < 256) {                         // ---- P blocks
        const int c = b >> 2, jq = b & 3;
        __shared__ __align__(16) float cm[D];
        {   // cm_c = mean over shots (float2 per thread)
            const int d = t * 2;
            float sx = 0.f, sy = 0.f;
#pragma unroll
            for (int j = 0; j < KSHOT; ++j) {
                float2 v = *(const float2*)(sup + (size_t)(c * KSHOT + j) * D + d);
                sx += v.x; sy += v.y;
            }
            cm[d] = sx * (1.0f / KSHOT); cm[d + 1] = sy * (1.0f / KSHOT);
        }
        __syncthreads();
        const int j = jq * 128 + (t >> 1);
        const int half = t & 1;
        const f32x4* wr = (const f32x4*)(W + (size_t)j * D + half * 256);
        const f32x4* cr = (const f32x4*)(cm + half * 256);
        float s = 0.f;
#pragma unroll 8
        for (int i = 0; i < 64; ++i) {
            f32x4 a = cr[i], wv = wr[i];
            s += a[0]*wv[0] + a[1]*wv[1] + a[2]*wv[2] + a[3]*wv[3];
        }
        s += __shfl_xor(s, 1);
        if (!half) {
            const float v = s + bias[j];
            const int sP = j >> 3;
            const int pos = (sP & ~7) | ((sP & 7) ^ (c & 7));
            Psw[c * 512 + pos * 8 + (j & 7)] = (bf16_t)v;
        }
        return;
    }

    {                                      // ---- W conversion, 4 rows/block
        const int n = (b - 256) * 4 + (t >> 6);
        const int sl = t & 63;
        const f32x4* wp = (const f32x4*)(W + (size_t)n * D + sl * 8);
        f32x4 v0 = wp[0], v1 = wp[1];
        bf16x8_t hv = { (bf16_t)v0[0], (bf16_t)v0[1], (bf16_t)v0[2], (bf16_t)v0[3],
                        (bf16_t)v1[0], (bf16_t)v1[1], (bf16_t)v1[2], (bf16_t)v1[3] };
        const int ck = sl >> 3, s = sl & 7;
        *(bf16x8_t*)(Bsw + (size_t)ck * 32768 + n * 64 + ((s ^ (n & 7)) * 8)) = hv;
    }
}

// ---------------------------------------------------------------- K_MAIN
// 256 blocks x 512 thr, 1 block/CU. Main GEMM (8 chunks, 512 cols) with
// double-buffered DMA; chunk 7's stage slot DMAs the 64KB Psw tile into
// Bb[0] (replacing the old G staging byte-for-byte). Epilogue: eq = acc+b
// -> bf16 transpose to LDS -> in-block cross-GEMM eq.P^T (128 MFMA) ->
// cross-wave reduce -> dist = qt - 2*cross + ||p~||^2.
__global__ __launch_bounds__(512, 2) void k_main(
    const float* __restrict__ query, const bf16_t* __restrict__ Bsw,
    const bf16_t* __restrict__ Psw, const float* __restrict__ bias,
    float* __restrict__ out)
{
    __shared__ __align__(16) bf16_t Bb[2][32768]; // 131,072 B
    __shared__ __align__(16) bf16_t Ab[2][2048];  //   8,192 B
    __shared__ float qln[4][32];    //     512 B
    __shared__ float phs[NWAY];     //     256 B
    __shared__ float bs[512];       //   2,048 B   (total 142,080 B -> 1/CU)

    const int t = threadIdx.x, bm = blockIdx.x;
    bs[t] = bias[t];

    const int l = t & 63, w = t >> 6;
    const int wm = w & 1, wn = w >> 1;
    const int r15 = l & 15, quad = l >> 4;

    const int xt0 = ((quad ^ (r15 & 7)) * 8);
    const int xt1 = (((4 + quad) ^ (r15 & 7)) * 8);
    const int aoff = (wm * 16 + r15) * 64;
    const int boff = (wn * 128 + r15) * 64;

    // ---- A preload: each thread owns row am, 4 cols per chunk, all 8 chunks
    const int am = t >> 4;                 // 0..31
    const int ac4 = t & 15;
    const int a_lds = am * 64 + (((ac4 >> 1) ^ (am & 7)) * 8) + (ac4 & 1) * 4;
    const float* aqp = query + (size_t)(bm * 32 + am) * D + ac4 * 4;

    bf16x4_t areg[8];
#pragma unroll
    for (int ck = 0; ck < 8; ++ck) {
        f32x4 v = *(const f32x4*)(aqp + ck * 64);
        areg[ck] = (bf16x4_t){ (bf16_t)v[0], (bf16_t)v[1], (bf16_t)v[2], (bf16_t)v[3] };
    }

    f32x4 acc[8];
#pragma unroll
    for (int i = 0; i < 8; ++i) acc[i] = (f32x4){0.f, 0.f, 0.f, 0.f};

    // ---- prologue: stage chunk 0 into buffer 0
    {
#pragma unroll
        for (int i = 0; i < 8; ++i) {
            const int off = t * 8 + i * 4096;
            ld16(Bsw + off, &Bb[0][off]);
        }
        *(bf16x4_t*)(&Ab[0][a_lds]) = areg[0];
    }
    __syncthreads();   // drains vmcnt(0)+lgkmcnt(0): chunk 0 ready

    // ---- main loop: issue-next / compute-current / one barrier per chunk
#pragma unroll
    for (int ck = 0; ck < 8; ++ck) {
        const int cur = ck & 1;
        if (ck < 7) {
            const int nxt = cur ^ 1;
            const size_t sb = (size_t)(ck + 1) * 32768;
#pragma unroll
            for (int i = 0; i < 8; ++i) {
                const int off = t * 8 + i * 4096;
                ld16(Bsw + sb + off, &Bb[nxt][off]);
            }
            *(bf16x4_t*)(&Ab[nxt][a_lds]) = areg[ck + 1];
        } else {
            // chunk-7 stage slot: DMA the P tile into Bb[0] (chunk 6's
            // reads of Bb[0] completed at the ck==6 barrier; chunk 7
            // computes from Bb[1])
#pragma unroll
            for (int i = 0; i < 8; ++i) {
                const int off = t * 8 + i * 4096;
                ld16(Psw + off, &Bb[0][off]);
            }
        }

        bf16x8_t a0 = *(const bf16x8_t*)(&Ab[cur][aoff + xt0]);
        bf16x8_t a1 = *(const bf16x8_t*)(&Ab[cur][aoff + xt1]);
#pragma unroll
        for (int tt = 0; tt < 8; ++tt) {
            bf16x8_t b0 = *(const bf16x8_t*)(&Bb[cur][boff + tt * 1024 + xt0]);
            bf16x8_t b1 = *(const bf16x8_t*)(&Bb[cur][boff + tt * 1024 + xt1]);
            acc[tt] = __builtin_amdgcn_mfma_f32_16x16x32_bf16(a0, b0, acc[tt], 0, 0, 0);
            acc[tt] = __builtin_amdgcn_mfma_f32_16x16x32_bf16(a1, b1, acc[tt], 0, 0, 0);
        }

        if (ck < 7) __syncthreads();
    }
    __syncthreads();   // drains P DMA; all chunk-7 reads of Bb[1] done

    // ---- epilogue part 1: eq = acc + bias -> qt partials + E' transpose ----
    // E' (32 rows x 512 k, bf16, row-swizzled) lives in Bb[1][0..16384)
    bf16_t* Ex = &Bb[1][0];
    float qp[4] = {0.f, 0.f, 0.f, 0.f};
#pragma unroll
    for (int tt = 0; tt < 8; ++tt) {
        const int k = wn * 128 + tt * 16 + r15;
        const int s = k >> 3, klo = k & 7;
        const float bv = bs[k];
#pragma unroll
        for (int reg = 0; reg < 4; ++reg) {
            const int row = wm * 16 + quad * 4 + reg;
            const float v = acc[tt][reg] + bv;
            qp[reg] += v * v;
            const int pos = (s & ~7) | ((s & 7) ^ (row & 7));
            Ex[row * 512 + pos * 8 + klo] = (bf16_t)v;
        }
    }
#pragma unroll
    for (int reg = 0; reg < 4; ++reg) {
        float s = qp[reg];
        s += __shfl_xor(s, 1); s += __shfl_xor(s, 2);
        s += __shfl_xor(s, 4); s += __shfl_xor(s, 8);
        if (r15 == 0) qln[wn][wm * 16 + quad * 4 + reg] = s;
    }

    // ---- ||p~||^2 from the staged bf16 P tile (permutation-invariant) ----
    if (t < NWAY) {
        const bf16_t* pr = &Bb[0][t * 512];
        float s2 = 0.f;
#pragma unroll
        for (int i = 0; i < 64; ++i) {
            bf16x8_t v = *(const bf16x8_t*)(pr + i * 8);
#pragma unroll
            for (int e = 0; e < 8; ++e) { float f = (float)v[e]; s2 += f * f; }
        }
        phs[t] = s2;
    }
    __syncthreads();

    // ---- epilogue part 2: cross-GEMM C[32x64] = eq . P^T ----
    // wave (wm,wn): rows wm*16..+16, k-slice wn*128..+128, all 64 classes
    f32x4 cacc[4];
#pragma unroll
    for (int ct = 0; ct < 4; ++ct) cacc[ct] = (f32x4){0.f, 0.f, 0.f, 0.f};
    const bf16_t* Pl = &Bb[0][0];
#pragma unroll
    for (int kk = 0; kk < 4; ++kk) {
        const int s = wn * 16 + kk * 4 + quad;               // k>>3
        const int pos = (s & ~7) | ((s & 7) ^ (r15 & 7));    // row&7 == r15&7
        bf16x8_t af = *(const bf16x8_t*)(Ex + (wm * 16 + r15) * 512 + pos * 8);
#pragma unroll
        for (int ct = 0; ct < 4; ++ct) {
            bf16x8_t bf = *(const bf16x8_t*)(Pl + (ct * 16 + r15) * 512 + pos * 8);
            cacc[ct] = __builtin_amdgcn_mfma_f32_16x16x32_bf16(af, bf, cacc[ct], 0, 0, 0);
        }
    }

    // ---- cross-wave (wn) reduction via LDS exchange in Bb[1][16384..) ----
    f32x4* ex = (f32x4*)&Bb[1][16384];   // 32 KB region, disjoint from Ex
#pragma unroll
    for (int ct = 0; ct < 4; ++ct)
        ex[((wm * 4 + ct) * 4 + wn) * 64 + l] = cacc[ct];
    __syncthreads();

    f32x4 cf = ex[((wm * 4 + wn) * 4 + 0) * 64 + l];
#pragma unroll
    for (int wnp = 1; wnp < 4; ++wnp)
        cf = cf + ex[((wm * 4 + wn) * 4 + wnp) * 64 + l];

    // ---- write dists: qt - 2*cross + ||p~||^2 ----
#pragma unroll
    for (int reg = 0; reg < 4; ++reg) {
        const int row_local = wm * 16 + quad * 4 + reg;
        const float qt = qln[0][row_local] + qln[1][row_local] +
                         qln[2][row_local] + qln[3][row_local];
        const int rowg = bm * 32 + row_local;
        const int c = wn * 16 + r15;
        out[(size_t)rowg * NWAY + c] = qt + phs[c] - 2.0f * cf[reg];
    }
}

// ---------------------------------------------------------------- launch
extern "C" void kernel_launch(void* const* d_in, const int* in_sizes, int n_in,
                              void* d_out, int out_size, void* d_ws, size_t ws_size,
                              hipStream_t stream)
{
    const float* support = (const float*)d_in[0];
    const float* query   = (const float*)d_in[1];
    const float* W       = (const float*)d_in[2];
    const float* bias    = (const float*)d_in[3];
    float* out = (float*)d_out;

    char* ws = (char*)d_ws;
    bf16_t* Bsw = (bf16_t*)ws;                    // 524,288 B
    bf16_t* Psw = (bf16_t*)(ws + 524288);         //  65,536 B

    k_prep<<<384, 256, 0, stream>>>(support, W, bias, Bsw, Psw);
    k_main<<<256, 512, 0, stream>>>(query, Bsw, Psw, bias, out);
}